// Round 25
// baseline (33.785 us; speedup 1.0000x reference)
//
#include <hip/hip_runtime.h>
#include <math.h>

#define B_  8
#define L_  4096
#define C_  256
#define TL  64

// ---- DPP wave-sum on the VALU pipe (verified R7/R9/R11) ----
template<int CTRL, int RM>
__device__ __forceinline__ float dpp_add(float v) {
    int mv = __builtin_amdgcn_update_dpp(0, __float_as_int(v), CTRL, RM, 0xf, true);
    return v + __int_as_float(mv);
}
__device__ __forceinline__ float wave_sum_hi(float v) {
    v = dpp_add<0xB1, 0xf>(v);   // quad_perm xor1
    v = dpp_add<0x4E, 0xf>(v);   // quad_perm xor2
    v = dpp_add<0x141, 0xf>(v);  // row_half_mirror
    v = dpp_add<0x140, 0xf>(v);  // row_mirror
    v = dpp_add<0x142, 0xa>(v);  // row_bcast15 -> rows 1,3
    v = dpp_add<0x143, 0xc>(v);  // row_bcast31 -> rows 2,3
    return v;
}
__device__ __forceinline__ float bcast63(float v) {
    return __int_as_float(__builtin_amdgcn_readlane(__float_as_int(v), 63));
}

// 512 threads = 8 waves; wave wv owns positions ll = wv*8 .. wv*8+7.
// TL=64: halves wave count vs R22 -> weight-load issue per position halves;
// 256B store segments. launch_bounds(512,2) -> 1 block/CU (8 waves, VGPR cap
// 256) with grid 512 = 2 staggered rounds (R22's proven regime).
__global__ __launch_bounds__(512, 2)
void dconv1d_kernel(const float* __restrict__ x,
                    const float* __restrict__ w_off,
                    const float* __restrict__ b_off,
                    const float* __restrict__ w_mask,
                    const float* __restrict__ b_mask,
                    float* __restrict__ out) {
    __shared__ float s_tile[TL * C_];   // 64 KB; full lane^row XOR swizzle

    const int tid  = threadIdx.x;
    const int lane = tid & 63;
    const int wv   = tid >> 6;          // wave 0..7
    const int wgid = blockIdx.x;
    const int b    = wgid & 7;          // batch == XCD (round-robin dispatch)
    const int l0   = (wgid >> 3) * TL;  // l-tile
    const float* __restrict__ xb = x + (size_t)b * L_ * C_;

    const float bo0 = b_off[0],  bo1 = b_off[1],  bo2 = b_off[2];
    const float bm0 = b_mask[0], bm1 = b_mask[1], bm2 = b_mask[2];

    const int c4  = lane << 2;          // lane's 4 channels
    const int lb8 = l0 + wv * 8;        // wave's first position

    // ---- 10 rows (lb8-1 .. lb8+8) loaded once: all 8 positions x 3 taps ----
    float4 xrow[10];
    #pragma unroll
    for (int rr = 0; rr < 10; ++rr) {
        const int row = lb8 - 1 + rr;
        if (row >= 0 && row < L_)
            xrow[rr] = *reinterpret_cast<const float4*>(
                xb + (size_t)row * C_ + c4);
        else
            xrow[rr] = make_float4(0.f, 0.f, 0.f, 0.f);
    }

    // ---- pass A: OFFSET conv (3 outputs, 8 positions, amortized weights) ----
    float sums_off[8][3];
    #pragma unroll
    for (int o = 0; o < 3; ++o) {
        const float4* wp = reinterpret_cast<const float4*>(
            w_off + o * (C_ * 3) + lane * 12);
        const float4 w0 = wp[0], w1 = wp[1], w2 = wp[2];
        float acc[8] = {0.f,0.f,0.f,0.f,0.f,0.f,0.f,0.f};
        #pragma unroll
        for (int rr = 0; rr < 10; ++rr) {
            #pragma unroll
            for (int tt = 0; tt < 3; ++tt) {
                const int i = rr - tt;             // compile-time per (rr,tt)
                if (i >= 0 && i < 8) {
                    const float wt0 = (tt==0)?w0.x:((tt==1)?w0.y:w0.z);
                    const float wt1 = (tt==0)?w0.w:((tt==1)?w1.x:w1.y);
                    const float wt2 = (tt==0)?w1.z:((tt==1)?w1.w:w2.x);
                    const float wt3 = (tt==0)?w2.y:((tt==1)?w2.z:w2.w);
                    acc[i] += xrow[rr].x * wt0 + xrow[rr].y * wt1
                            + xrow[rr].z * wt2 + xrow[rr].w * wt3;
                }
            }
        }
        #pragma unroll
        for (int i = 0; i < 8; ++i)
            sums_off[i][o] = bcast63(wave_sum_hi(acc[i]));
    }

    // ---- issue g0 gathers (positions 0..3) - fly during mask conv ----
    float4 gxf0[4][3], gxc0[4][3];
    float  alp0[4][3];
    #pragma unroll
    for (int i = 0; i < 4; ++i) {
        const int l = lb8 + i;
        #pragma unroll
        for (int k = 0; k < 3; ++k) {
            const float bo = (k == 0) ? bo0 : ((k == 1) ? bo1 : bo2);
            const float off = sums_off[i][k] + bo;
            const float pos = fminf(fmaxf((float)l + off, 0.0f), (float)(L_ - 1));
            const float flf = floorf(pos);
            const int   fl  = (int)flf;
            const int   ce  = min(fl + 1, L_ - 1);
            alp0[i][k] = pos - flf;
            gxf0[i][k] = *reinterpret_cast<const float4*>(
                xb + (size_t)fl * C_ + c4);
            gxc0[i][k] = *reinterpret_cast<const float4*>(
                xb + (size_t)ce * C_ + c4);
        }
    }

    // ---- pass B: MASK conv (3 outputs, 8 positions) while g0 in flight ----
    float sums_msk[8][3];
    #pragma unroll
    for (int o = 0; o < 3; ++o) {
        const float4* wp = reinterpret_cast<const float4*>(
            w_mask + o * (C_ * 3) + lane * 12);
        const float4 w0 = wp[0], w1 = wp[1], w2 = wp[2];
        float acc[8] = {0.f,0.f,0.f,0.f,0.f,0.f,0.f,0.f};
        #pragma unroll
        for (int rr = 0; rr < 10; ++rr) {
            #pragma unroll
            for (int tt = 0; tt < 3; ++tt) {
                const int i = rr - tt;
                if (i >= 0 && i < 8) {
                    const float wt0 = (tt==0)?w0.x:((tt==1)?w0.y:w0.z);
                    const float wt1 = (tt==0)?w0.w:((tt==1)?w1.x:w1.y);
                    const float wt2 = (tt==0)?w1.z:((tt==1)?w1.w:w2.x);
                    const float wt3 = (tt==0)?w2.y:((tt==1)?w2.z:w2.w);
                    acc[i] += xrow[rr].x * wt0 + xrow[rr].y * wt1
                            + xrow[rr].z * wt2 + xrow[rr].w * wt3;
                }
            }
        }
        #pragma unroll
        for (int i = 0; i < 8; ++i)
            sums_msk[i][o] = bcast63(wave_sum_hi(acc[i]));
    }

    // ---- issue g1 gathers (positions 4..7) - fly during combine g0 ----
    float4 gxf1[4][3], gxc1[4][3];
    float  alp1[4][3];
    #pragma unroll
    for (int i = 0; i < 4; ++i) {
        const int l = lb8 + 4 + i;
        #pragma unroll
        for (int k = 0; k < 3; ++k) {
            const float bo = (k == 0) ? bo0 : ((k == 1) ? bo1 : bo2);
            const float off = sums_off[4 + i][k] + bo;
            const float pos = fminf(fmaxf((float)l + off, 0.0f), (float)(L_ - 1));
            const float flf = floorf(pos);
            const int   fl  = (int)flf;
            const int   ce  = min(fl + 1, L_ - 1);
            alp1[i][k] = pos - flf;
            gxf1[i][k] = *reinterpret_cast<const float4*>(
                xb + (size_t)fl * C_ + c4);
            gxc1[i][k] = *reinterpret_cast<const float4*>(
                xb + (size_t)ce * C_ + c4);
        }
    }

    // ---- combine g0 (hides g1) ----
    #pragma unroll
    for (int i = 0; i < 4; ++i) {
        const int ll = wv * 8 + i;
        float4 v = make_float4(0.f, 0.f, 0.f, 0.f);
        #pragma unroll
        for (int k = 0; k < 3; ++k) {
            const float bm = (k == 0) ? bm0 : ((k == 1) ? bm1 : bm2);
            const float m  = 1.0f / (1.0f + __expf(-(sums_msk[i][k] + bm)));
            const float a  = alp0[i][k];
            const float wf = m * (1.0f - a);
            const float wc = m * a;
            v.x += wf * gxf0[i][k].x + wc * gxc0[i][k].x;
            v.y += wf * gxf0[i][k].y + wc * gxc0[i][k].y;
            v.z += wf * gxf0[i][k].z + wc * gxc0[i][k].z;
            v.w += wf * gxf0[i][k].w + wc * gxc0[i][k].w;
        }
        *reinterpret_cast<float4*>(
            &s_tile[ll * C_ + ((lane ^ ll) << 2)]) = v;
    }

    // ---- combine g1 ----
    #pragma unroll
    for (int i = 0; i < 4; ++i) {
        const int ll = wv * 8 + 4 + i;
        float4 v = make_float4(0.f, 0.f, 0.f, 0.f);
        #pragma unroll
        for (int k = 0; k < 3; ++k) {
            const float bm = (k == 0) ? bm0 : ((k == 1) ? bm1 : bm2);
            const float m  = 1.0f / (1.0f + __expf(-(sums_msk[4 + i][k] + bm)));
            const float a  = alp1[i][k];
            const float wf = m * (1.0f - a);
            const float wc = m * a;
            v.x += wf * gxf1[i][k].x + wc * gxc1[i][k].x;
            v.y += wf * gxf1[i][k].y + wc * gxc1[i][k].y;
            v.z += wf * gxf1[i][k].z + wc * gxc1[i][k].z;
            v.w += wf * gxf1[i][k].w + wc * gxc1[i][k].w;
        }
        *reinterpret_cast<float4*>(
            &s_tile[ll * C_ + ((lane ^ ll) << 2)]) = v;
    }
    __syncthreads();

    // ---- phase 3: transpose write-out, 256B segments along l ----
    // thread = (row lw 0..63, granule stream wv); 8 sweeps over granules.
    {
        const int lw = lane;               // row 0..63
        #pragma unroll
        for (int s = 0; s < 8; ++s) {
            const int q  = wv + (s << 3);  // granule 0..63 (channels 4q..4q+3)
            const int gr = q ^ lw;
            const float4 v = *reinterpret_cast<const float4*>(
                &s_tile[lw * C_ + (gr << 2)]);
            const size_t ob = ((size_t)b * C_ + (q << 2)) * L_ + l0 + lw;
            out[ob]          = v.x;
            out[ob + L_]     = v.y;
            out[ob + 2 * L_] = v.z;
            out[ob + 3 * L_] = v.w;
        }
    }
}

extern "C" void kernel_launch(void* const* d_in, const int* in_sizes, int n_in,
                              void* d_out, int out_size, void* d_ws, size_t ws_size,
                              hipStream_t stream) {
    const float* x      = (const float*)d_in[0];
    const float* w_off  = (const float*)d_in[1];
    const float* b_off  = (const float*)d_in[2];
    const float* w_mask = (const float*)d_in[3];
    const float* b_mask = (const float*)d_in[4];
    float* out = (float*)d_out;

    dconv1d_kernel<<<(L_ / TL) * B_, 512, 0, stream>>>(
        x, w_off, b_off, w_mask, b_mask, out);
}

// Round 26
// 26.648 us; speedup vs baseline: 1.2678x; 1.2678x over previous
//
#include <hip/hip_runtime.h>
#include <math.h>

#define B_  8
#define L_  4096
#define C_  256
#define TL  32

// ---- DPP wave-sum on the VALU pipe (verified R7/R9/R11) ----
template<int CTRL, int RM>
__device__ __forceinline__ float dpp_add(float v) {
    int mv = __builtin_amdgcn_update_dpp(0, __float_as_int(v), CTRL, RM, 0xf, true);
    return v + __int_as_float(mv);
}
__device__ __forceinline__ float wave_sum_hi(float v) {
    v = dpp_add<0xB1, 0xf>(v);   // quad_perm xor1
    v = dpp_add<0x4E, 0xf>(v);   // quad_perm xor2
    v = dpp_add<0x141, 0xf>(v);  // row_half_mirror
    v = dpp_add<0x140, 0xf>(v);  // row_mirror
    v = dpp_add<0x142, 0xa>(v);  // row_bcast15 -> rows 1,3
    v = dpp_add<0x143, 0xc>(v);  // row_bcast31 -> rows 2,3
    return v;
}
__device__ __forceinline__ float bcast63(float v) {
    return __int_as_float(__builtin_amdgcn_readlane(__float_as_int(v), 63));
}

// 512 threads = 8 waves; wave wv owns positions ll = wv*4 .. wv*4+3.
// Session-best structure (R22, 26.98us):
//  - split conv: offset conv -> ISSUE 24 gathers -> mask conv hides their
//    latency -> combine (the only successful latency-overlap lever, +2%)
//  - scalar accumulators, one conv output at a time (no spill; R11 +20%)
//  - DPP wave-reduce on VALU pipe + readlane->SGPR broadcast (R7 +8%)
//  - XCD-bound 1D grid (b = wgid&7), granule-XOR LDS tile (0 conflicts),
//    full-128B-line transpose stores (exact 32.8MB WRITE)
//  - launch_bounds(512,2): VGPR cap 256 so in-flight gathers stay in regs
__global__ __launch_bounds__(512, 2)
void dconv1d_kernel(const float* __restrict__ x,
                    const float* __restrict__ w_off,
                    const float* __restrict__ b_off,
                    const float* __restrict__ w_mask,
                    const float* __restrict__ b_mask,
                    float* __restrict__ out) {
    __shared__ float s_tile[TL * C_];   // 32 KB; XOR-granule swizzle (0 conflicts)

    const int tid  = threadIdx.x;
    const int lane = tid & 63;
    const int wv   = tid >> 6;          // wave 0..7
    const int wgid = blockIdx.x;
    const int b    = wgid & 7;          // batch == XCD (round-robin dispatch)
    const int l0   = (wgid >> 3) * TL;  // l-tile
    const float* __restrict__ xb = x + (size_t)b * L_ * C_;

    const float bo0 = b_off[0],  bo1 = b_off[1],  bo2 = b_off[2];
    const float bm0 = b_mask[0], bm1 = b_mask[1], bm2 = b_mask[2];

    const int c4  = lane << 2;          // lane's 4 channels
    const int lb4 = l0 + wv * 4;        // wave's first position

    // ---- 6 x-rows (taps -1..+1 of 4 positions) loaded once ----
    float4 xrow[6];
    #pragma unroll
    for (int rr = 0; rr < 6; ++rr) {
        const int row = lb4 - 1 + rr;
        if (row >= 0 && row < L_)
            xrow[rr] = *reinterpret_cast<const float4*>(
                xb + (size_t)row * C_ + c4);
        else
            xrow[rr] = make_float4(0.f, 0.f, 0.f, 0.f);
    }

    // ---- pass A: OFFSET conv (3 outputs) -> sums_off (SGPR-uniform) ----
    float sums_off[4][3];
    #pragma unroll
    for (int o = 0; o < 3; ++o) {
        const float4* wp = reinterpret_cast<const float4*>(
            w_off + o * (C_ * 3) + lane * 12);
        const float4 w0 = wp[0], w1 = wp[1], w2 = wp[2];
        float acc[4] = {0.f, 0.f, 0.f, 0.f};
        #pragma unroll
        for (int rr = 0; rr < 6; ++rr) {
            #pragma unroll
            for (int tt = 0; tt < 3; ++tt) {
                const int i = rr - tt;             // compile-time per (rr,tt)
                if (i >= 0 && i < 4) {
                    const float wt0 = (tt==0)?w0.x:((tt==1)?w0.y:w0.z);
                    const float wt1 = (tt==0)?w0.w:((tt==1)?w1.x:w1.y);
                    const float wt2 = (tt==0)?w1.z:((tt==1)?w1.w:w2.x);
                    const float wt3 = (tt==0)?w2.y:((tt==1)?w2.z:w2.w);
                    acc[i] += xrow[rr].x * wt0 + xrow[rr].y * wt1
                            + xrow[rr].z * wt2 + xrow[rr].w * wt3;
                }
            }
        }
        #pragma unroll
        for (int i = 0; i < 4; ++i)
            sums_off[i][o] = bcast63(wave_sum_hi(acc[i]));
    }

    // ---- ISSUE all 24 gather loads now (addresses need only sums_off);
    //      they fly during pass B ----
    float4 gxf[4][3], gxc[4][3];
    float  alp[4][3];
    #pragma unroll
    for (int i = 0; i < 4; ++i) {
        const int l = lb4 + i;
        #pragma unroll
        for (int k = 0; k < 3; ++k) {
            const float bo = (k == 0) ? bo0 : ((k == 1) ? bo1 : bo2);
            const float off = sums_off[i][k] + bo;
            const float pos = fminf(fmaxf((float)l + off, 0.0f), (float)(L_ - 1));
            const float flf = floorf(pos);
            const int   fl  = (int)flf;
            const int   ce  = min(fl + 1, L_ - 1);
            alp[i][k] = pos - flf;
            gxf[i][k] = *reinterpret_cast<const float4*>(
                xb + (size_t)fl * C_ + c4);
            gxc[i][k] = *reinterpret_cast<const float4*>(
                xb + (size_t)ce * C_ + c4);
        }
    }

    // ---- pass B: MASK conv (3 outputs) while gathers are in flight ----
    float sums_msk[4][3];
    #pragma unroll
    for (int o = 0; o < 3; ++o) {
        const float4* wp = reinterpret_cast<const float4*>(
            w_mask + o * (C_ * 3) + lane * 12);
        const float4 w0 = wp[0], w1 = wp[1], w2 = wp[2];
        float acc[4] = {0.f, 0.f, 0.f, 0.f};
        #pragma unroll
        for (int rr = 0; rr < 6; ++rr) {
            #pragma unroll
            for (int tt = 0; tt < 3; ++tt) {
                const int i = rr - tt;
                if (i >= 0 && i < 4) {
                    const float wt0 = (tt==0)?w0.x:((tt==1)?w0.y:w0.z);
                    const float wt1 = (tt==0)?w0.w:((tt==1)?w1.x:w1.y);
                    const float wt2 = (tt==0)?w1.z:((tt==1)?w1.w:w2.x);
                    const float wt3 = (tt==0)?w2.y:((tt==1)?w2.z:w2.w);
                    acc[i] += xrow[rr].x * wt0 + xrow[rr].y * wt1
                            + xrow[rr].z * wt2 + xrow[rr].w * wt3;
                }
            }
        }
        #pragma unroll
        for (int i = 0; i < 4; ++i)
            sums_msk[i][o] = bcast63(wave_sum_hi(acc[i]));
    }

    // ---- combine: gathers have landed; lerp + mask + tile store ----
    #pragma unroll
    for (int i = 0; i < 4; ++i) {
        const int ll = wv * 4 + i;
        float4 v = make_float4(0.f, 0.f, 0.f, 0.f);
        #pragma unroll
        for (int k = 0; k < 3; ++k) {
            const float bm = (k == 0) ? bm0 : ((k == 1) ? bm1 : bm2);
            const float m  = 1.0f / (1.0f + __expf(-(sums_msk[i][k] + bm)));
            const float a  = alp[i][k];
            const float wf = m * (1.0f - a);
            const float wc = m * a;
            const float4 xf = gxf[i][k];
            const float4 xc = gxc[i][k];
            v.x += wf * xf.x + wc * xc.x;
            v.y += wf * xf.y + wc * xc.y;
            v.z += wf * xf.z + wc * xc.z;
            v.w += wf * xf.w + wc * xc.w;
        }
        const int gr = lane ^ (ll & 15);   // 16B-granule swizzle
        *reinterpret_cast<float4*>(&s_tile[ll * C_ + (gr << 2)]) = v;
    }
    __syncthreads();

    // ---- phase 3: transpose write-out, full 128B lines along l ----
    {
        const int lw = tid & 31;
        const int q0 = tid >> 5;           // 0..15
        #pragma unroll
        for (int s = 0; s < 4; ++s) {
            const int q  = q0 + (s << 4);  // 0..63 (channels 4q..4q+3)
            const int gr = q ^ (lw & 15);
            const float4 v = *reinterpret_cast<const float4*>(
                &s_tile[lw * C_ + (gr << 2)]);
            const size_t ob = ((size_t)b * C_ + (q << 2)) * L_ + l0 + lw;
            out[ob]          = v.x;
            out[ob + L_]     = v.y;
            out[ob + 2 * L_] = v.z;
            out[ob + 3 * L_] = v.w;
        }
    }
}

extern "C" void kernel_launch(void* const* d_in, const int* in_sizes, int n_in,
                              void* d_out, int out_size, void* d_ws, size_t ws_size,
                              hipStream_t stream) {
    const float* x      = (const float*)d_in[0];
    const float* w_off  = (const float*)d_in[1];
    const float* b_off  = (const float*)d_in[2];
    const float* w_mask = (const float*)d_in[3];
    const float* b_mask = (const float*)d_in[4];
    float* out = (float*)d_out;

    dconv1d_kernel<<<(L_ / TL) * B_, 512, 0, stream>>>(
        x, w_off, b_off, w_mask, b_mask, out);
}